// Round 7
// baseline (132.392 us; speedup 1.0000x reference)
//
#include <hip/hip_runtime.h>
#include <hip/hip_bf16.h>
#include <math.h>

#define N 4096
#define D 128
#define NJ 4
#define KTOP 16

typedef __attribute__((ext_vector_type(8))) short bf16x8;
typedef __attribute__((ext_vector_type(4))) float f32x4;

// ws layout (ncs = 8 when ws >= 13MB, 4 when >= 9MB, else 2):
//   [0, 1MB)   fh   bf16 [N][D]       normalized feature rows, row-major
//   [1MB, 5MB) gh   bf16 [NJ][N*D]    normalized negative rows, FRAGMENT-MAJOR:
//              per j, per 64-cand chunk chg (64 chunks): 16 frags x 512 ushorts.
//   [5MB, ..)  top  f32  [NJ][N][ncs][16] partial sorted top-16 per col-split

__device__ __forceinline__ void ce_desc(float* a, int i, int l) {
    float x = a[i], y = a[l];
    a[i] = fmaxf(x, y);
    a[l] = fminf(x, y);
}

// Batcher odd-even mergesort of 16 (descending), 63 compare-exchanges.
// Harness-verified (absmax 0.0 at R2/R3, 0.00195 at R4).
__device__ __forceinline__ void sort16_desc(float* a) {
    // sort(0,8)
    ce_desc(a,0,1);  ce_desc(a,2,3);  ce_desc(a,0,2);  ce_desc(a,1,3);  ce_desc(a,1,2);
    ce_desc(a,4,5);  ce_desc(a,6,7);  ce_desc(a,4,6);  ce_desc(a,5,7);  ce_desc(a,5,6);
    ce_desc(a,0,4);  ce_desc(a,2,6);  ce_desc(a,2,4);  ce_desc(a,1,5);  ce_desc(a,3,7);
    ce_desc(a,3,5);  ce_desc(a,1,2);  ce_desc(a,3,4);  ce_desc(a,5,6);
    // sort(8,8)
    ce_desc(a,8,9);  ce_desc(a,10,11); ce_desc(a,8,10); ce_desc(a,9,11); ce_desc(a,9,10);
    ce_desc(a,12,13); ce_desc(a,14,15); ce_desc(a,12,14); ce_desc(a,13,15); ce_desc(a,13,14);
    ce_desc(a,8,12); ce_desc(a,10,14); ce_desc(a,10,12); ce_desc(a,9,13); ce_desc(a,11,15);
    ce_desc(a,11,13); ce_desc(a,9,10); ce_desc(a,11,12); ce_desc(a,13,14);
    // oddEvenMerge(0,16,1)
    ce_desc(a,0,8);  ce_desc(a,4,12); ce_desc(a,4,8);  ce_desc(a,2,10); ce_desc(a,6,14);
    ce_desc(a,6,10); ce_desc(a,2,4);  ce_desc(a,6,8);  ce_desc(a,10,12);
    ce_desc(a,1,9);  ce_desc(a,5,13); ce_desc(a,5,9);  ce_desc(a,3,11); ce_desc(a,7,15);
    ce_desc(a,7,11); ce_desc(a,3,5);  ce_desc(a,7,9);  ce_desc(a,11,13);
    ce_desc(a,1,2);  ce_desc(a,3,4);  ce_desc(a,5,6);  ce_desc(a,7,8);  ce_desc(a,9,10);
    ce_desc(a,11,12); ce_desc(a,13,14);
}

// clean a bitonic 16-sequence into descending order (32 CE)
__device__ __forceinline__ void bitonic_clean16_desc(float* a) {
    #pragma unroll
    for (int jj = 8; jj > 0; jj >>= 1) {
        #pragma unroll
        for (int i = 0; i < 16; i++) {
            int l = i ^ jj;
            if (l > i) {
                float x = a[i], y = a[l];
                a[i] = fmaxf(x, y);
                a[l] = fminf(x, y);
            }
        }
    }
}

// ---------------- prep: fp32 L2-normalize -> bf16 (R4-proven, VERBATIM) ----------------
__global__ __launch_bounds__(256) void neguni_prep(
    const float* __restrict__ feat, const float* __restrict__ negs,
    unsigned short* __restrict__ fh, unsigned short* __restrict__ gh,
    float* __restrict__ out)
{
    __shared__ unsigned short lbuf[8192];   // 16KB chunk staging

    if (blockIdx.x == 0 && threadIdx.x == 0) *out = 0.f;   // replaces memset dispatch

    if (blockIdx.x < 256) {
        const int w    = threadIdx.x >> 6;
        const int lane = threadIdx.x & 63;
        const int p    = lane & 15;
        const int rr   = lane >> 4;
        const int row  = blockIdx.x * 16 + w * 4 + rr;   // 0..4095

        const float* src = feat + (size_t)row * D;
        float4 v0 = ((const float4*)src)[p * 2];
        float4 v1 = ((const float4*)src)[p * 2 + 1];
        float ss = v0.x*v0.x + v0.y*v0.y + v0.z*v0.z + v0.w*v0.w
                 + v1.x*v1.x + v1.y*v1.y + v1.z*v1.z + v1.w*v1.w;
        ss += __shfl_xor(ss, 1, 64);
        ss += __shfl_xor(ss, 2, 64);
        ss += __shfl_xor(ss, 4, 64);
        ss += __shfl_xor(ss, 8, 64);
        const float inv = 1.0f / fmaxf(sqrtf(ss), 1e-12f);

        float f[8] = {v0.x, v0.y, v0.z, v0.w, v1.x, v1.y, v1.z, v1.w};
        unsigned int u[4];
        #pragma unroll
        for (int i = 0; i < 4; i++) {
            __hip_bfloat16 b0 = __float2bfloat16(f[2*i]   * inv);
            __hip_bfloat16 b1 = __float2bfloat16(f[2*i+1] * inv);
            u[i] = ((unsigned int)*(unsigned short*)&b1 << 16) | *(unsigned short*)&b0;
        }
        uint4 pk; pk.x = u[0]; pk.y = u[1]; pk.z = u[2]; pk.w = u[3];
        *(uint4*)(fh + (size_t)row * D + p * 8) = pk;
    } else {
        const int c   = blockIdx.x - 256;    // 0..255
        const int j   = c >> 6;
        const int chg = c & 63;
        const int t   = threadIdx.x;
        const int lr  = t >> 2;              // local row 0..63
        const int p4  = t & 3;               // 32-float piece within row

        const float* src = negs + ((size_t)(j * 4096 + chg * 64 + lr)) * D + p4 * 32;
        float4 v[8];
        float ss = 0.f;
        #pragma unroll
        for (int i = 0; i < 8; i++) {
            v[i] = ((const float4*)src)[i];
            ss += v[i].x*v[i].x + v[i].y*v[i].y + v[i].z*v[i].z + v[i].w*v[i].w;
        }
        ss += __shfl_xor(ss, 1, 64);
        ss += __shfl_xor(ss, 2, 64);
        const float inv = 1.0f / fmaxf(sqrtf(ss), 1e-12f);

        float f[32];
        #pragma unroll
        for (int i = 0; i < 8; i++) {
            f[4*i]   = v[i].x; f[4*i+1] = v[i].y;
            f[4*i+2] = v[i].z; f[4*i+3] = v[i].w;
        }

        const int t16 = lr >> 4;
        const int col = lr & 15;
        #pragma unroll
        for (int qq = 0; qq < 4; qq++) {
            unsigned int uu[4];
            #pragma unroll
            for (int h = 0; h < 4; h++) {
                __hip_bfloat16 b0 = __float2bfloat16(f[qq*8 + 2*h]     * inv);
                __hip_bfloat16 b1 = __float2bfloat16(f[qq*8 + 2*h + 1] * inv);
                uu[h] = ((unsigned int)*(unsigned short*)&b1 << 16) | *(unsigned short*)&b0;
            }
            uint4 pk; pk.x = uu[0]; pk.y = uu[1]; pk.z = uu[2]; pk.w = uu[3];
            *(uint4*)(lbuf + (p4 * 4 + t16) * 512 + (qq * 16 + col) * 8) = pk;
        }
        __syncthreads();

        uint4* dst = (uint4*)(gh + (size_t)j * N * D + (size_t)chg * 8192);
        const uint4* sb = (const uint4*)lbuf;
        dst[t]       = sb[t];
        dst[t + 256] = sb[t + 256];
        dst[t + 512] = sb[t + 512];
        dst[t + 768] = sb[t + 768];
    }
}

// ---------------- main: shared-A LDS double-buffer + MFMA + lane-local top-16 ----------
// R4-proven body, VERBATIM. Only the grid grows (ncs=8 -> 2048 blocks): LDS 32KB/block
// caps residency at 5 blocks/CU = 20 waves/CU (vs R4's 4 blocks/16 waves), attacking the
// measured 54% VALUBusy / 25% occupancy stall with a deeper wave pool + backfill.
__global__ __launch_bounds__(256, 4) void neguni_main(
    const unsigned short* __restrict__ fh, const unsigned short* __restrict__ gh,
    const int* __restrict__ target, const int* __restrict__ idxp,
    float* __restrict__ topbuf, int ncs, int nch)
{
    __shared__ unsigned short lbuf[2][8192];   // 2 x 16KB A-chunk double buffer

    const int tid   = threadIdx.x;
    const int w     = tid >> 6;
    const int lane  = tid & 63;
    const int col16 = lane & 15;
    const int quad  = lane >> 4;

    const int bid = blockIdx.x;
    const int j   = bid & 3;
    const int ft  = (bid >> 2) & 63;
    const int cs  = bid >> 8;                  // 0..ncs-1
    const int r0  = ft * 64;
    const int row = r0 + w * 16 + col16;
    const int c0  = cs * nch * 64;
    const int idx = idxp[0];
    const bool msk = (j == idx);

    bf16x8 bfr[4];
    {
        const unsigned short* fr = fh + (size_t)row * D + quad * 8;
        bfr[0] = *(const bf16x8*)(fr);
        bfr[1] = *(const bf16x8*)(fr + 32);
        bfr[2] = *(const bf16x8*)(fr + 64);
        bfr[3] = *(const bf16x8*)(fr + 96);
    }
    const int rtg = target[row];

    const unsigned short* gcs = gh + (size_t)j * N * D + (size_t)cs * nch * 8192;

    float lst[KTOP];

    // stage chunk 0 into buffer 0
    {
        const unsigned short* gsrc = gcs + w * 2048 + lane * 8;
        unsigned short* ldst = &lbuf[0][w * 2048];
        #pragma unroll
        for (int i = 0; i < 4; i++) {
            __builtin_amdgcn_global_load_lds(
                (const __attribute__((address_space(1))) void*)(gsrc + i * 512),
                (__attribute__((address_space(3))) void*)(ldst + i * 512),
                16, 0, 0);
        }
    }

    #pragma unroll 1
    for (int ch = 0; ch < nch; ch++) {
        __syncthreads();   // implicit vmcnt(0): buf[ch&1] staged; prev reads done

        if (ch < nch - 1) {
            const unsigned short* gsrc = gcs + (size_t)(ch + 1) * 8192 + w * 2048 + lane * 8;
            unsigned short* ldst = &lbuf[(ch + 1) & 1][w * 2048];
            #pragma unroll
            for (int i = 0; i < 4; i++) {
                __builtin_amdgcn_global_load_lds(
                    (const __attribute__((address_space(1))) void*)(gsrc + i * 512),
                    (__attribute__((address_space(3))) void*)(ldst + i * 512),
                    16, 0, 0);
            }
        }

        const unsigned short* lb = &lbuf[ch & 1][0];
        f32x4 acc[4];
        #pragma unroll
        for (int t = 0; t < 4; t++) acc[t] = (f32x4){0.f, 0.f, 0.f, 0.f};
        #pragma unroll
        for (int s = 0; s < 4; s++) {
            #pragma unroll
            for (int t = 0; t < 4; t++) {
                bf16x8 a = *(const bf16x8*)(lb + (s * 4 + t) * 512 + lane * 8);
                acc[t] = __builtin_amdgcn_mfma_f32_16x16x32_bf16(a, bfr[s], acc[t], 0, 0, 0);
            }
        }

        const int cbase = c0 + ch * 64;
        float s16[16];
        #pragma unroll
        for (int t = 0; t < 4; t++) {
            s16[t * 4 + 0] = acc[t][0];
            s16[t * 4 + 1] = acc[t][1];
            s16[t * 4 + 2] = acc[t][2];
            s16[t * 4 + 3] = acc[t][3];
        }
        if (msk) {
            #pragma unroll
            for (int t = 0; t < 4; t++) {
                int4 tc = *(const int4*)(target + cbase + t * 16 + quad * 4);
                if (tc.x == rtg) s16[t * 4 + 0] = -1e9f;
                if (tc.y == rtg) s16[t * 4 + 1] = -1e9f;
                if (tc.z == rtg) s16[t * 4 + 2] = -1e9f;
                if (tc.w == rtg) s16[t * 4 + 3] = -1e9f;
            }
        }

        sort16_desc(s16);
        if (ch == 0) {
            #pragma unroll
            for (int i = 0; i < 16; i++) lst[i] = s16[i];
        } else {
            #pragma unroll
            for (int i = 0; i < 16; i++) lst[i] = fmaxf(lst[i], s16[15 - i]);
            bitonic_clean16_desc(lst);
        }
    }

    // intra-wave merge across quads (lanes with same col16): 2 shfl levels
    #pragma unroll
    for (int off = 16; off <= 32; off <<= 1) {
        float mg[16];
        #pragma unroll
        for (int i = 0; i < 16; i++)
            mg[i] = fmaxf(lst[i], __shfl_xor(lst[15 - i], off, 64));
        bitonic_clean16_desc(mg);
        #pragma unroll
        for (int i = 0; i < 16; i++) lst[i] = mg[i];
    }

    if (quad == 0) {
        float* outp = topbuf + (((size_t)j * N + row) * ncs + cs) * KTOP;
        #pragma unroll
        for (int k = 0; k < KTOP; k++) outp[k] = lst[k];
    }
}

// ---------------- finalize: up-to-8-way merge of partials + entropy reduce -------------
// ncs<=4: the R4-proven direct 4-way path (lists 0..3 of buf, sentinels for unused).
// ncs==8: per-thread pairwise 2-way pre-merges (8 -> 4 lists, same two-pointer pattern)
// into buf2, then the identical proven 4-way on buf2.
__global__ __launch_bounds__(64) void neguni_fin(
    const float* __restrict__ topbuf, float* __restrict__ out, int ncs)
{
    __shared__ float buf[64][8 * 17];   // 8 lists x (16 + tail sentinel) per thread
    __shared__ float buf2[64][4 * 17];  // pre-merged lists (ncs==8 path)
    __shared__ float mm[16][65];        // merged [row_l][k*4+j], padded

    const int t     = threadIdx.x;      // 0..63
    const int j     = t >> 4;           // 0..3
    const int row_l = t & 15;           // 0..15
    const int row   = blockIdx.x * 16 + row_l;

    #pragma unroll
    for (int c = 0; c < 8; c++) {
        if (c < ncs) {
            const float4* src = (const float4*)(topbuf + (((size_t)j * N + row) * ncs + c) * KTOP);
            #pragma unroll
            for (int q = 0; q < 4; q++) {
                float4 v = src[q];
                buf[t][c * 17 + q * 4 + 0] = v.x;
                buf[t][c * 17 + q * 4 + 1] = v.y;
                buf[t][c * 17 + q * 4 + 2] = v.z;
                buf[t][c * 17 + q * 4 + 3] = v.w;
            }
        } else {
            // fully sentinel-fill unused lists (heads may be walked by the mergers)
            #pragma unroll
            for (int q = 0; q < 16; q++) buf[t][c * 17 + q] = -3.0e38f;
        }
        buf[t][c * 17 + 16] = -3.0e38f;  // tail sentinel
    }

    if (ncs == 8) {
        // pairwise pre-merge (2c, 2c+1) -> buf2 list c  (per-thread, no races)
        #pragma unroll
        for (int c = 0; c < 4; c++) {
            int ia = (2 * c) * 17, ib = (2 * c + 1) * 17;
            #pragma unroll
            for (int k = 0; k < KTOP; k++) {
                float va = buf[t][ia], vb = buf[t][ib];
                bool ta = va >= vb;
                buf2[t][c * 17 + k] = ta ? va : vb;
                if (ta) ia++; else ib++;
            }
            buf2[t][c * 17 + 16] = -3.0e38f;
        }
    }

    {
        const float* bb = (ncs == 8) ? buf2[t] : buf[t];
        int i0 = 0, i1 = 17, i2 = 34, i3 = 51;
        #pragma unroll
        for (int k = 0; k < KTOP; k++) {
            float v0 = bb[i0], v1 = bb[i1];
            float v2 = bb[i2], v3 = bb[i3];
            float m01 = fmaxf(v0, v1), m23 = fmaxf(v2, v3);
            float mx  = fmaxf(m01, m23);
            if      (mx == v0) i0++;
            else if (mx == v1) i1++;
            else if (mx == v2) i2++;
            else               i3++;
            mm[row_l][k * 4 + j] = mx;
        }
    }
    __syncthreads();

    float val = 0.f;
    #pragma unroll
    for (int i = 0; i < 4; i++) {
        const int idx2 = t + i * 64;          // 0..255
        const int rl   = idx2 & 15;
        const int k    = idx2 >> 4;           // 0..15
        float l0 = mm[rl][k * 4 + 0] * 100.0f;
        float l1 = mm[rl][k * 4 + 1] * 100.0f;
        float l2 = mm[rl][k * 4 + 2] * 100.0f;
        float l3 = mm[rl][k * 4 + 3] * 100.0f;
        float m  = fmaxf(fmaxf(l0, l1), fmaxf(l2, l3));
        float d0 = l0 - m, d1 = l1 - m, d2 = l2 - m, d3 = l3 - m;
        float e0 = __expf(d0), e1 = __expf(d1), e2 = __expf(d2), e3 = __expf(d3);
        float s  = e0 + e1 + e2 + e3;
        float ent = (e0 * d0 + e1 * d1 + e2 * d2 + e3 * d3) / s - __logf(s);
        float dk  = __expf(-0.05129329439f * (float)k);   // 0.95^k
        val += ent * dk;
    }
    val *= (1.0f / (11.1974666f * (float)N));   // Ssum = (1-0.95^16)/0.05

    #pragma unroll
    for (int off = 32; off > 0; off >>= 1) val += __shfl_xor(val, off, 64);
    if (t == 0) {
        atomicAdd(out, val);
        if (blockIdx.x == 0) atomicAdd(out, 1.38629436112f);   // log(4)
    }
}

extern "C" void kernel_launch(void* const* d_in, const int* in_sizes, int n_in,
                              void* d_out, int out_size, void* d_ws, size_t ws_size,
                              hipStream_t stream) {
    const float* feat   = (const float*)d_in[0];
    const int*   target = (const int*)d_in[1];
    const float* negs   = (const float*)d_in[2];
    const int*   idxp   = (const int*)d_in[3];
    float* out = (float*)d_out;

    unsigned short* fh = (unsigned short*)d_ws;
    unsigned short* gh = fh + (size_t)N * D;                  // +1 MB
    float* topbuf      = (float*)(gh + (size_t)NJ * N * D);   // +5 MB

    // topbuf = NJ*N*ncs*16*4 B: ncs=8 -> 8MB (ws 13MB), ncs=4 -> 4MB (ws 9MB).
    // Deterministic in ws_size only: identical under graph capture.
    const int ncs = (ws_size >= (size_t)13 * 1024 * 1024) ? 8
                  : (ws_size >= (size_t)9  * 1024 * 1024) ? 4 : 2;
    const int nch = 64 / ncs;   // 64-cand chunks per block

    neguni_prep<<<dim3(512), dim3(256), 0, stream>>>(feat, negs, fh, gh, out);
    neguni_main<<<dim3(NJ * 64 * ncs), dim3(256), 0, stream>>>(fh, gh, target, idxp, topbuf, ncs, nch);
    neguni_fin<<<dim3(N / 16), dim3(64), 0, stream>>>(topbuf, out, ncs);
}

// Round 9
// 122.994 us; speedup vs baseline: 1.0764x; 1.0764x over previous
//
#include <hip/hip_runtime.h>
#include <hip/hip_bf16.h>
#include <math.h>

#define N 4096
#define D 128
#define NJ 4
#define KTOP 16

typedef __attribute__((ext_vector_type(8))) short bf16x8;
typedef __attribute__((ext_vector_type(4))) float f32x4;
typedef __attribute__((ext_vector_type(2))) _Float16 h2f;   // packed f16 pair

// ws layout (ncs = 8 when ws >= 13MB, 4 when >= 9MB, else 2):
//   [0, 1MB)   fh   bf16 [N][D]       normalized feature rows, row-major
//   [1MB, 5MB) gh   bf16 [NJ][N*D]    normalized negative rows, FRAGMENT-MAJOR:
//              per j, per 64-cand chunk chg (64 chunks): 16 frags x 512 ushorts.
//   [5MB, ..)  top  f32  [NJ][N][ncs][16] partial sorted top-16 per col-split

// clean a bitonic 16-sequence into descending order (32 CE, f32) — proven
__device__ __forceinline__ void bitonic_clean16_desc(float* a) {
    #pragma unroll
    for (int jj = 8; jj > 0; jj >>= 1) {
        #pragma unroll
        for (int i = 0; i < 16; i++) {
            int l = i ^ jj;
            if (l > i) {
                float x = a[i], y = a[l];
                a[i] = fmaxf(x, y);
                a[l] = fminf(x, y);
            }
        }
    }
}

// ---- packed-f16 dual-stream primitives: each CE handles BOTH f16 lanes ----
// __builtin_elementwise_max/min on _Float16 vectors -> v_pk_max_f16 / v_pk_min_f16
// (1+1 insts per CE for two independent streams = half the f32 cost).
// No hip_fp16.h: its __hmax2 overload set collides with hip_bf16.h (R8 compile fail).
__device__ __forceinline__ void ce2_desc(h2f* a, int i, int l) {
    h2f x = a[i], y = a[l];
    a[i] = __builtin_elementwise_max(x, y);
    a[l] = __builtin_elementwise_min(x, y);
}

// Batcher odd-even mergesort of 8 (descending), 19 CE, both lanes in lockstep
__device__ __forceinline__ void sort8_desc_h2(h2f* a) {
    ce2_desc(a,0,1); ce2_desc(a,2,3); ce2_desc(a,0,2); ce2_desc(a,1,3); ce2_desc(a,1,2);
    ce2_desc(a,4,5); ce2_desc(a,6,7); ce2_desc(a,4,6); ce2_desc(a,5,7); ce2_desc(a,5,6);
    ce2_desc(a,0,4); ce2_desc(a,1,5); ce2_desc(a,2,6); ce2_desc(a,3,7);
    ce2_desc(a,2,4); ce2_desc(a,3,5);
    ce2_desc(a,1,2); ce2_desc(a,3,4); ce2_desc(a,5,6);
}

// clean a bitonic 16-sequence into descending order (32 CE), both lanes
__device__ __forceinline__ void clean16_desc_h2(h2f* a) {
    #pragma unroll
    for (int jj = 8; jj > 0; jj >>= 1) {
        #pragma unroll
        for (int i = 0; i < 16; i++) {
            int l = i ^ jj;
            if (l > i) ce2_desc(a, i, l);
        }
    }
}

// ---------------- prep: fp32 L2-normalize -> bf16 (R4/R7-proven, VERBATIM) -------------
__global__ __launch_bounds__(256) void neguni_prep(
    const float* __restrict__ feat, const float* __restrict__ negs,
    unsigned short* __restrict__ fh, unsigned short* __restrict__ gh,
    float* __restrict__ out)
{
    __shared__ unsigned short lbuf[8192];   // 16KB chunk staging

    if (blockIdx.x == 0 && threadIdx.x == 0) *out = 0.f;   // replaces memset dispatch

    if (blockIdx.x < 256) {
        const int w    = threadIdx.x >> 6;
        const int lane = threadIdx.x & 63;
        const int p    = lane & 15;
        const int rr   = lane >> 4;
        const int row  = blockIdx.x * 16 + w * 4 + rr;   // 0..4095

        const float* src = feat + (size_t)row * D;
        float4 v0 = ((const float4*)src)[p * 2];
        float4 v1 = ((const float4*)src)[p * 2 + 1];
        float ss = v0.x*v0.x + v0.y*v0.y + v0.z*v0.z + v0.w*v0.w
                 + v1.x*v1.x + v1.y*v1.y + v1.z*v1.z + v1.w*v1.w;
        ss += __shfl_xor(ss, 1, 64);
        ss += __shfl_xor(ss, 2, 64);
        ss += __shfl_xor(ss, 4, 64);
        ss += __shfl_xor(ss, 8, 64);
        const float inv = 1.0f / fmaxf(sqrtf(ss), 1e-12f);

        float f[8] = {v0.x, v0.y, v0.z, v0.w, v1.x, v1.y, v1.z, v1.w};
        unsigned int u[4];
        #pragma unroll
        for (int i = 0; i < 4; i++) {
            __hip_bfloat16 b0 = __float2bfloat16(f[2*i]   * inv);
            __hip_bfloat16 b1 = __float2bfloat16(f[2*i+1] * inv);
            u[i] = ((unsigned int)*(unsigned short*)&b1 << 16) | *(unsigned short*)&b0;
        }
        uint4 pk; pk.x = u[0]; pk.y = u[1]; pk.z = u[2]; pk.w = u[3];
        *(uint4*)(fh + (size_t)row * D + p * 8) = pk;
    } else {
        const int c   = blockIdx.x - 256;    // 0..255
        const int j   = c >> 6;
        const int chg = c & 63;
        const int t   = threadIdx.x;
        const int lr  = t >> 2;              // local row 0..63
        const int p4  = t & 3;               // 32-float piece within row

        const float* src = negs + ((size_t)(j * 4096 + chg * 64 + lr)) * D + p4 * 32;
        float4 v[8];
        float ss = 0.f;
        #pragma unroll
        for (int i = 0; i < 8; i++) {
            v[i] = ((const float4*)src)[i];
            ss += v[i].x*v[i].x + v[i].y*v[i].y + v[i].z*v[i].z + v[i].w*v[i].w;
        }
        ss += __shfl_xor(ss, 1, 64);
        ss += __shfl_xor(ss, 2, 64);
        const float inv = 1.0f / fmaxf(sqrtf(ss), 1e-12f);

        float f[32];
        #pragma unroll
        for (int i = 0; i < 8; i++) {
            f[4*i]   = v[i].x; f[4*i+1] = v[i].y;
            f[4*i+2] = v[i].z; f[4*i+3] = v[i].w;
        }

        const int t16 = lr >> 4;
        const int col = lr & 15;
        #pragma unroll
        for (int qq = 0; qq < 4; qq++) {
            unsigned int uu[4];
            #pragma unroll
            for (int h = 0; h < 4; h++) {
                __hip_bfloat16 b0 = __float2bfloat16(f[qq*8 + 2*h]     * inv);
                __hip_bfloat16 b1 = __float2bfloat16(f[qq*8 + 2*h + 1] * inv);
                uu[h] = ((unsigned int)*(unsigned short*)&b1 << 16) | *(unsigned short*)&b0;
            }
            uint4 pk; pk.x = uu[0]; pk.y = uu[1]; pk.z = uu[2]; pk.w = uu[3];
            *(uint4*)(lbuf + (p4 * 4 + t16) * 512 + (qq * 16 + col) * 8) = pk;
        }
        __syncthreads();

        uint4* dst = (uint4*)(gh + (size_t)j * N * D + (size_t)chg * 8192);
        const uint4* sb = (const uint4*)lbuf;
        dst[t]       = sb[t];
        dst[t + 256] = sb[t + 256];
        dst[t + 512] = sb[t + 512];
        dst[t + 768] = sb[t + 768];
    }
}

// ---------------- main: shared-A LDS double-buffer + MFMA + packed-f16 top-16 ----------
// R7 DMA/MFMA structure VERBATIM. Selection: each lane's 16 chunk values split into
// two 8-value sub-streams (A=acc[0..1], B=acc[2..3]); two independent top-16 lists
// live in the two f16 lanes of h2f regs. Each CE = pk_max+pk_min on both streams
// -> per-chunk sort pipeline 206 -> ~126 VALU insts. Mask fill -60000 (finite in
// f16; union of per-stream top-16s >= top-16 of union). Halves merge once, in
// proven f32 code, after the loop.
__global__ __launch_bounds__(256, 4) void neguni_main(
    const unsigned short* __restrict__ fh, const unsigned short* __restrict__ gh,
    const int* __restrict__ target, const int* __restrict__ idxp,
    float* __restrict__ topbuf, int ncs, int nch)
{
    __shared__ unsigned short lbuf[2][8192];   // 2 x 16KB A-chunk double buffer

    const int tid   = threadIdx.x;
    const int w     = tid >> 6;
    const int lane  = tid & 63;
    const int col16 = lane & 15;
    const int quad  = lane >> 4;

    const int bid = blockIdx.x;
    const int j   = bid & 3;
    const int ft  = (bid >> 2) & 63;
    const int cs  = bid >> 8;                  // 0..ncs-1
    const int r0  = ft * 64;
    const int row = r0 + w * 16 + col16;
    const int c0  = cs * nch * 64;
    const int idx = idxp[0];
    const bool msk = (j == idx);

    bf16x8 bfr[4];
    {
        const unsigned short* fr = fh + (size_t)row * D + quad * 8;
        bfr[0] = *(const bf16x8*)(fr);
        bfr[1] = *(const bf16x8*)(fr + 32);
        bfr[2] = *(const bf16x8*)(fr + 64);
        bfr[3] = *(const bf16x8*)(fr + 96);
    }
    const int rtg = target[row];

    const unsigned short* gcs = gh + (size_t)j * N * D + (size_t)cs * nch * 8192;

    // dual-stream packed top-16 state: lane0 = stream A, lane1 = stream B
    h2f lst[16];
    #pragma unroll
    for (int i = 0; i < 16; i++) lst[i] = (h2f){(_Float16)(-60000.0f), (_Float16)(-60000.0f)};

    // stage chunk 0 into buffer 0
    {
        const unsigned short* gsrc = gcs + w * 2048 + lane * 8;
        unsigned short* ldst = &lbuf[0][w * 2048];
        #pragma unroll
        for (int i = 0; i < 4; i++) {
            __builtin_amdgcn_global_load_lds(
                (const __attribute__((address_space(1))) void*)(gsrc + i * 512),
                (__attribute__((address_space(3))) void*)(ldst + i * 512),
                16, 0, 0);
        }
    }

    #pragma unroll 1
    for (int ch = 0; ch < nch; ch++) {
        __syncthreads();   // implicit vmcnt(0): buf[ch&1] staged; prev reads done

        if (ch < nch - 1) {
            const unsigned short* gsrc = gcs + (size_t)(ch + 1) * 8192 + w * 2048 + lane * 8;
            unsigned short* ldst = &lbuf[(ch + 1) & 1][w * 2048];
            #pragma unroll
            for (int i = 0; i < 4; i++) {
                __builtin_amdgcn_global_load_lds(
                    (const __attribute__((address_space(1))) void*)(gsrc + i * 512),
                    (__attribute__((address_space(3))) void*)(ldst + i * 512),
                    16, 0, 0);
            }
        }

        const unsigned short* lb = &lbuf[ch & 1][0];
        f32x4 acc[4];
        #pragma unroll
        for (int t = 0; t < 4; t++) acc[t] = (f32x4){0.f, 0.f, 0.f, 0.f};
        #pragma unroll
        for (int s = 0; s < 4; s++) {
            #pragma unroll
            for (int t = 0; t < 4; t++) {
                bf16x8 a = *(const bf16x8*)(lb + (s * 4 + t) * 512 + lane * 8);
                acc[t] = __builtin_amdgcn_mfma_f32_16x16x32_bf16(a, bfr[s], acc[t], 0, 0, 0);
            }
        }

        // gather + mask in f32 (structure verbatim; mask fill -60000, f16-finite)
        const int cbase = c0 + ch * 64;
        float s16[16];
        #pragma unroll
        for (int t = 0; t < 4; t++) {
            s16[t * 4 + 0] = acc[t][0];
            s16[t * 4 + 1] = acc[t][1];
            s16[t * 4 + 2] = acc[t][2];
            s16[t * 4 + 3] = acc[t][3];
        }
        if (msk) {
            #pragma unroll
            for (int t = 0; t < 4; t++) {
                int4 tc = *(const int4*)(target + cbase + t * 16 + quad * 4);
                if (tc.x == rtg) s16[t * 4 + 0] = -60000.0f;
                if (tc.y == rtg) s16[t * 4 + 1] = -60000.0f;
                if (tc.z == rtg) s16[t * 4 + 2] = -60000.0f;
                if (tc.w == rtg) s16[t * 4 + 3] = -60000.0f;
            }
        }

        // pack the two streams: lane0 = s16[q] (A), lane1 = s16[8+q] (B)
        h2f nb[8];
        #pragma unroll
        for (int q = 0; q < 8; q++) {
            h2f v;
            v[0] = (_Float16)s16[q];
            v[1] = (_Float16)s16[8 + q];
            nb[q] = v;
        }

        sort8_desc_h2(nb);
        // top-16 of (sorted-16 lst) U (sorted-8 nb), per lane: positions 0..7
        // unchanged (nb implicitly -inf-padded), 8..15 take max(lst, nb reversed).
        #pragma unroll
        for (int q = 0; q < 8; q++)
            lst[8 + q] = __builtin_elementwise_max(lst[8 + q], nb[7 - q]);
        clean16_desc_h2(lst);
    }

    // unpack the two streams and merge once in proven f32 code
    float fa[16], fb[16];
    #pragma unroll
    for (int i = 0; i < 16; i++) {
        fa[i] = (float)lst[i][0];
        fb[i] = (float)lst[i][1];
    }
    float fl[16];
    #pragma unroll
    for (int i = 0; i < 16; i++) fl[i] = fmaxf(fa[i], fb[15 - i]);
    bitonic_clean16_desc(fl);

    // intra-wave merge across quads (lanes with same col16): 2 shfl levels (proven)
    #pragma unroll
    for (int off = 16; off <= 32; off <<= 1) {
        float mg[16];
        #pragma unroll
        for (int i = 0; i < 16; i++)
            mg[i] = fmaxf(fl[i], __shfl_xor(fl[15 - i], off, 64));
        bitonic_clean16_desc(mg);
        #pragma unroll
        for (int i = 0; i < 16; i++) fl[i] = mg[i];
    }

    if (quad == 0) {
        float* outp = topbuf + (((size_t)j * N + row) * ncs + cs) * KTOP;
        #pragma unroll
        for (int k = 0; k < KTOP; k++) outp[k] = fl[k];
    }
}

// ---------------- finalize: up-to-8-way merge + entropy reduce (R7-proven, VERBATIM) ---
__global__ __launch_bounds__(64) void neguni_fin(
    const float* __restrict__ topbuf, float* __restrict__ out, int ncs)
{
    __shared__ float buf[64][8 * 17];   // 8 lists x (16 + tail sentinel) per thread
    __shared__ float buf2[64][4 * 17];  // pre-merged lists (ncs==8 path)
    __shared__ float mm[16][65];        // merged [row_l][k*4+j], padded

    const int t     = threadIdx.x;      // 0..63
    const int j     = t >> 4;           // 0..3
    const int row_l = t & 15;           // 0..15
    const int row   = blockIdx.x * 16 + row_l;

    #pragma unroll
    for (int c = 0; c < 8; c++) {
        if (c < ncs) {
            const float4* src = (const float4*)(topbuf + (((size_t)j * N + row) * ncs + c) * KTOP);
            #pragma unroll
            for (int q = 0; q < 4; q++) {
                float4 v = src[q];
                buf[t][c * 17 + q * 4 + 0] = v.x;
                buf[t][c * 17 + q * 4 + 1] = v.y;
                buf[t][c * 17 + q * 4 + 2] = v.z;
                buf[t][c * 17 + q * 4 + 3] = v.w;
            }
        } else {
            #pragma unroll
            for (int q = 0; q < 16; q++) buf[t][c * 17 + q] = -3.0e38f;
        }
        buf[t][c * 17 + 16] = -3.0e38f;  // tail sentinel
    }

    if (ncs == 8) {
        #pragma unroll
        for (int c = 0; c < 4; c++) {
            int ia = (2 * c) * 17, ib = (2 * c + 1) * 17;
            #pragma unroll
            for (int k = 0; k < KTOP; k++) {
                float va = buf[t][ia], vb = buf[t][ib];
                bool ta = va >= vb;
                buf2[t][c * 17 + k] = ta ? va : vb;
                if (ta) ia++; else ib++;
            }
            buf2[t][c * 17 + 16] = -3.0e38f;
        }
    }

    {
        const float* bb = (ncs == 8) ? buf2[t] : buf[t];
        int i0 = 0, i1 = 17, i2 = 34, i3 = 51;
        #pragma unroll
        for (int k = 0; k < KTOP; k++) {
            float v0 = bb[i0], v1 = bb[i1];
            float v2 = bb[i2], v3 = bb[i3];
            float m01 = fmaxf(v0, v1), m23 = fmaxf(v2, v3);
            float mx  = fmaxf(m01, m23);
            if      (mx == v0) i0++;
            else if (mx == v1) i1++;
            else if (mx == v2) i2++;
            else               i3++;
            mm[row_l][k * 4 + j] = mx;
        }
    }
    __syncthreads();

    float val = 0.f;
    #pragma unroll
    for (int i = 0; i < 4; i++) {
        const int idx2 = t + i * 64;          // 0..255
        const int rl   = idx2 & 15;
        const int k    = idx2 >> 4;           // 0..15
        float l0 = mm[rl][k * 4 + 0] * 100.0f;
        float l1 = mm[rl][k * 4 + 1] * 100.0f;
        float l2 = mm[rl][k * 4 + 2] * 100.0f;
        float l3 = mm[rl][k * 4 + 3] * 100.0f;
        float m  = fmaxf(fmaxf(l0, l1), fmaxf(l2, l3));
        float d0 = l0 - m, d1 = l1 - m, d2 = l2 - m, d3 = l3 - m;
        float e0 = __expf(d0), e1 = __expf(d1), e2 = __expf(d2), e3 = __expf(d3);
        float s  = e0 + e1 + e2 + e3;
        float ent = (e0 * d0 + e1 * d1 + e2 * d2 + e3 * d3) / s - __logf(s);
        float dk  = __expf(-0.05129329439f * (float)k);   // 0.95^k
        val += ent * dk;
    }
    val *= (1.0f / (11.1974666f * (float)N));   // Ssum = (1-0.95^16)/0.05

    #pragma unroll
    for (int off = 32; off > 0; off >>= 1) val += __shfl_xor(val, off, 64);
    if (t == 0) {
        atomicAdd(out, val);
        if (blockIdx.x == 0) atomicAdd(out, 1.38629436112f);   // log(4)
    }
}

extern "C" void kernel_launch(void* const* d_in, const int* in_sizes, int n_in,
                              void* d_out, int out_size, void* d_ws, size_t ws_size,
                              hipStream_t stream) {
    const float* feat   = (const float*)d_in[0];
    const int*   target = (const int*)d_in[1];
    const float* negs   = (const float*)d_in[2];
    const int*   idxp   = (const int*)d_in[3];
    float* out = (float*)d_out;

    unsigned short* fh = (unsigned short*)d_ws;
    unsigned short* gh = fh + (size_t)N * D;                  // +1 MB
    float* topbuf      = (float*)(gh + (size_t)NJ * N * D);   // +5 MB

    // topbuf = NJ*N*ncs*16*4 B: ncs=8 -> 8MB (ws 13MB), ncs=4 -> 4MB (ws 9MB).
    // Deterministic in ws_size only: identical under graph capture.
    const int ncs = (ws_size >= (size_t)13 * 1024 * 1024) ? 8
                  : (ws_size >= (size_t)9  * 1024 * 1024) ? 4 : 2;
    const int nch = 64 / ncs;   // 64-cand chunks per block

    neguni_prep<<<dim3(512), dim3(256), 0, stream>>>(feat, negs, fh, gh, out);
    neguni_main<<<dim3(NJ * 64 * ncs), dim3(256), 0, stream>>>(fh, gh, target, idxp, topbuf, ncs, nch);
    neguni_fin<<<dim3(N / 16), dim3(64), 0, stream>>>(topbuf, out, ncs);
}

// Round 10
// 120.307 us; speedup vs baseline: 1.1005x; 1.0223x over previous
//
#include <hip/hip_runtime.h>
#include <hip/hip_bf16.h>
#include <math.h>

#define N 4096
#define D 128
#define NJ 4
#define KTOP 16

typedef __attribute__((ext_vector_type(8))) short bf16x8;
typedef __attribute__((ext_vector_type(4))) float f32x4;
// exact return element type of __builtin_amdgcn_cvt_pkrtz (clang 'E2h'):
typedef __attribute__((ext_vector_type(2))) __fp16 h2f;

// ws layout (ncs = 8 when ws >= 13MB, 4 when >= 9MB, else 2):
//   [0, 1MB)   fh   bf16 [N][D]       normalized feature rows, row-major
//   [1MB, 5MB) gh   bf16 [NJ][N*D]    normalized negative rows, FRAGMENT-MAJOR:
//              per j, per 64-cand chunk chg (64 chunks): 16 frags x 512 ushorts.
//   [5MB, ..)  top  f32  [NJ][N][ncs][16] partial sorted top-16 per col-split

// clean a bitonic 16-sequence into descending order (32 CE, f32) — proven
__device__ __forceinline__ void bitonic_clean16_desc(float* a) {
    #pragma unroll
    for (int jj = 8; jj > 0; jj >>= 1) {
        #pragma unroll
        for (int i = 0; i < 16; i++) {
            int l = i ^ jj;
            if (l > i) {
                float x = a[i], y = a[l];
                a[i] = fmaxf(x, y);
                a[l] = fminf(x, y);
            }
        }
    }
}

// ---- packed-f16 dual-stream primitives: each CE handles BOTH f16 lanes ----
// __builtin_elementwise_max/min on __fp16 vectors -> v_pk_max_f16 / v_pk_min_f16
// (1+1 insts per CE for two independent streams = half the f32 cost).
// No hip_fp16.h: its __hmax2 overload set collides with hip_bf16.h (R8 compile fail).
__device__ __forceinline__ void ce2_desc(h2f* a, int i, int l) {
    h2f x = a[i], y = a[l];
    a[i] = __builtin_elementwise_max(x, y);
    a[l] = __builtin_elementwise_min(x, y);
}

// Batcher odd-even mergesort of 8 (descending), 19 CE, both lanes in lockstep
__device__ __forceinline__ void sort8_desc_h2(h2f* a) {
    ce2_desc(a,0,1); ce2_desc(a,2,3); ce2_desc(a,0,2); ce2_desc(a,1,3); ce2_desc(a,1,2);
    ce2_desc(a,4,5); ce2_desc(a,6,7); ce2_desc(a,4,6); ce2_desc(a,5,7); ce2_desc(a,5,6);
    ce2_desc(a,0,4); ce2_desc(a,1,5); ce2_desc(a,2,6); ce2_desc(a,3,7);
    ce2_desc(a,2,4); ce2_desc(a,3,5);
    ce2_desc(a,1,2); ce2_desc(a,3,4); ce2_desc(a,5,6);
}

// clean a bitonic 16-sequence into descending order (32 CE), both lanes
__device__ __forceinline__ void clean16_desc_h2(h2f* a) {
    #pragma unroll
    for (int jj = 8; jj > 0; jj >>= 1) {
        #pragma unroll
        for (int i = 0; i < 16; i++) {
            int l = i ^ jj;
            if (l > i) ce2_desc(a, i, l);
        }
    }
}

// ---------------- prep: fp32 L2-normalize -> bf16 (R4/R7-proven, VERBATIM) -------------
__global__ __launch_bounds__(256) void neguni_prep(
    const float* __restrict__ feat, const float* __restrict__ negs,
    unsigned short* __restrict__ fh, unsigned short* __restrict__ gh,
    float* __restrict__ out)
{
    __shared__ unsigned short lbuf[8192];   // 16KB chunk staging

    if (blockIdx.x == 0 && threadIdx.x == 0) *out = 0.f;   // replaces memset dispatch

    if (blockIdx.x < 256) {
        const int w    = threadIdx.x >> 6;
        const int lane = threadIdx.x & 63;
        const int p    = lane & 15;
        const int rr   = lane >> 4;
        const int row  = blockIdx.x * 16 + w * 4 + rr;   // 0..4095

        const float* src = feat + (size_t)row * D;
        float4 v0 = ((const float4*)src)[p * 2];
        float4 v1 = ((const float4*)src)[p * 2 + 1];
        float ss = v0.x*v0.x + v0.y*v0.y + v0.z*v0.z + v0.w*v0.w
                 + v1.x*v1.x + v1.y*v1.y + v1.z*v1.z + v1.w*v1.w;
        ss += __shfl_xor(ss, 1, 64);
        ss += __shfl_xor(ss, 2, 64);
        ss += __shfl_xor(ss, 4, 64);
        ss += __shfl_xor(ss, 8, 64);
        const float inv = 1.0f / fmaxf(sqrtf(ss), 1e-12f);

        float f[8] = {v0.x, v0.y, v0.z, v0.w, v1.x, v1.y, v1.z, v1.w};
        unsigned int u[4];
        #pragma unroll
        for (int i = 0; i < 4; i++) {
            __hip_bfloat16 b0 = __float2bfloat16(f[2*i]   * inv);
            __hip_bfloat16 b1 = __float2bfloat16(f[2*i+1] * inv);
            u[i] = ((unsigned int)*(unsigned short*)&b1 << 16) | *(unsigned short*)&b0;
        }
        uint4 pk; pk.x = u[0]; pk.y = u[1]; pk.z = u[2]; pk.w = u[3];
        *(uint4*)(fh + (size_t)row * D + p * 8) = pk;
    } else {
        const int c   = blockIdx.x - 256;    // 0..255
        const int j   = c >> 6;
        const int chg = c & 63;
        const int t   = threadIdx.x;
        const int lr  = t >> 2;              // local row 0..63
        const int p4  = t & 3;               // 32-float piece within row

        const float* src = negs + ((size_t)(j * 4096 + chg * 64 + lr)) * D + p4 * 32;
        float4 v[8];
        float ss = 0.f;
        #pragma unroll
        for (int i = 0; i < 8; i++) {
            v[i] = ((const float4*)src)[i];
            ss += v[i].x*v[i].x + v[i].y*v[i].y + v[i].z*v[i].z + v[i].w*v[i].w;
        }
        ss += __shfl_xor(ss, 1, 64);
        ss += __shfl_xor(ss, 2, 64);
        const float inv = 1.0f / fmaxf(sqrtf(ss), 1e-12f);

        float f[32];
        #pragma unroll
        for (int i = 0; i < 8; i++) {
            f[4*i]   = v[i].x; f[4*i+1] = v[i].y;
            f[4*i+2] = v[i].z; f[4*i+3] = v[i].w;
        }

        const int t16 = lr >> 4;
        const int col = lr & 15;
        #pragma unroll
        for (int qq = 0; qq < 4; qq++) {
            unsigned int uu[4];
            #pragma unroll
            for (int h = 0; h < 4; h++) {
                __hip_bfloat16 b0 = __float2bfloat16(f[qq*8 + 2*h]     * inv);
                __hip_bfloat16 b1 = __float2bfloat16(f[qq*8 + 2*h + 1] * inv);
                uu[h] = ((unsigned int)*(unsigned short*)&b1 << 16) | *(unsigned short*)&b0;
            }
            uint4 pk; pk.x = uu[0]; pk.y = uu[1]; pk.z = uu[2]; pk.w = uu[3];
            *(uint4*)(lbuf + (p4 * 4 + t16) * 512 + (qq * 16 + col) * 8) = pk;
        }
        __syncthreads();

        uint4* dst = (uint4*)(gh + (size_t)j * N * D + (size_t)chg * 8192);
        const uint4* sb = (const uint4*)lbuf;
        dst[t]       = sb[t];
        dst[t + 256] = sb[t + 256];
        dst[t + 512] = sb[t + 512];
        dst[t + 768] = sb[t + 768];
    }
}

// ---------------- main: shared-A LDS double-buffer + MFMA + packed-f16 top-16 ----------
// R9 structure VERBATIM except packing: f32->packed-f16 via v_cvt_pkrtz_f16_f32
// (1 inst per pair vs cvt+cvt+pack = 3) — selection pipeline ~134 -> ~118 insts/chunk.
// RTZ is monotone, so selection differs from RN by <= 1 ulp (R9 margin: absmax 0.0).
__global__ __launch_bounds__(256, 4) void neguni_main(
    const unsigned short* __restrict__ fh, const unsigned short* __restrict__ gh,
    const int* __restrict__ target, const int* __restrict__ idxp,
    float* __restrict__ topbuf, int ncs, int nch)
{
    __shared__ unsigned short lbuf[2][8192];   // 2 x 16KB A-chunk double buffer

    const int tid   = threadIdx.x;
    const int w     = tid >> 6;
    const int lane  = tid & 63;
    const int col16 = lane & 15;
    const int quad  = lane >> 4;

    const int bid = blockIdx.x;
    const int j   = bid & 3;
    const int ft  = (bid >> 2) & 63;
    const int cs  = bid >> 8;                  // 0..ncs-1
    const int r0  = ft * 64;
    const int row = r0 + w * 16 + col16;
    const int c0  = cs * nch * 64;
    const int idx = idxp[0];
    const bool msk = (j == idx);

    bf16x8 bfr[4];
    {
        const unsigned short* fr = fh + (size_t)row * D + quad * 8;
        bfr[0] = *(const bf16x8*)(fr);
        bfr[1] = *(const bf16x8*)(fr + 32);
        bfr[2] = *(const bf16x8*)(fr + 64);
        bfr[3] = *(const bf16x8*)(fr + 96);
    }
    const int rtg = target[row];

    const unsigned short* gcs = gh + (size_t)j * N * D + (size_t)cs * nch * 8192;

    // dual-stream packed top-16 state: lane0 = stream A, lane1 = stream B
    h2f lst[16];
    #pragma unroll
    for (int i = 0; i < 16; i++) lst[i] = (h2f){(__fp16)(-60000.0f), (__fp16)(-60000.0f)};

    // stage chunk 0 into buffer 0
    {
        const unsigned short* gsrc = gcs + w * 2048 + lane * 8;
        unsigned short* ldst = &lbuf[0][w * 2048];
        #pragma unroll
        for (int i = 0; i < 4; i++) {
            __builtin_amdgcn_global_load_lds(
                (const __attribute__((address_space(1))) void*)(gsrc + i * 512),
                (__attribute__((address_space(3))) void*)(ldst + i * 512),
                16, 0, 0);
        }
    }

    #pragma unroll 1
    for (int ch = 0; ch < nch; ch++) {
        __syncthreads();   // implicit vmcnt(0): buf[ch&1] staged; prev reads done

        if (ch < nch - 1) {
            const unsigned short* gsrc = gcs + (size_t)(ch + 1) * 8192 + w * 2048 + lane * 8;
            unsigned short* ldst = &lbuf[(ch + 1) & 1][w * 2048];
            #pragma unroll
            for (int i = 0; i < 4; i++) {
                __builtin_amdgcn_global_load_lds(
                    (const __attribute__((address_space(1))) void*)(gsrc + i * 512),
                    (__attribute__((address_space(3))) void*)(ldst + i * 512),
                    16, 0, 0);
            }
        }

        const unsigned short* lb = &lbuf[ch & 1][0];
        f32x4 acc[4];
        #pragma unroll
        for (int t = 0; t < 4; t++) acc[t] = (f32x4){0.f, 0.f, 0.f, 0.f};
        #pragma unroll
        for (int s = 0; s < 4; s++) {
            #pragma unroll
            for (int t = 0; t < 4; t++) {
                bf16x8 a = *(const bf16x8*)(lb + (s * 4 + t) * 512 + lane * 8);
                acc[t] = __builtin_amdgcn_mfma_f32_16x16x32_bf16(a, bfr[s], acc[t], 0, 0, 0);
            }
        }

        // gather + mask in f32 (structure verbatim; mask fill -60000, f16-finite)
        const int cbase = c0 + ch * 64;
        float s16[16];
        #pragma unroll
        for (int t = 0; t < 4; t++) {
            s16[t * 4 + 0] = acc[t][0];
            s16[t * 4 + 1] = acc[t][1];
            s16[t * 4 + 2] = acc[t][2];
            s16[t * 4 + 3] = acc[t][3];
        }
        if (msk) {
            #pragma unroll
            for (int t = 0; t < 4; t++) {
                int4 tc = *(const int4*)(target + cbase + t * 16 + quad * 4);
                if (tc.x == rtg) s16[t * 4 + 0] = -60000.0f;
                if (tc.y == rtg) s16[t * 4 + 1] = -60000.0f;
                if (tc.z == rtg) s16[t * 4 + 2] = -60000.0f;
                if (tc.w == rtg) s16[t * 4 + 3] = -60000.0f;
            }
        }

        // pack the two streams in ONE inst/pair: lane0 = s16[q] (A), lane1 = s16[8+q] (B)
        h2f nb[8];
        #pragma unroll
        for (int q = 0; q < 8; q++)
            nb[q] = __builtin_amdgcn_cvt_pkrtz(s16[q], s16[8 + q]);

        sort8_desc_h2(nb);
        // top-16 of (sorted-16 lst) U (sorted-8 nb), per lane: positions 0..7
        // unchanged (nb implicitly -inf-padded), 8..15 take max(lst, nb reversed).
        #pragma unroll
        for (int q = 0; q < 8; q++)
            lst[8 + q] = __builtin_elementwise_max(lst[8 + q], nb[7 - q]);
        clean16_desc_h2(lst);
    }

    // unpack the two streams and merge once in proven f32 code
    float fa[16], fb[16];
    #pragma unroll
    for (int i = 0; i < 16; i++) {
        fa[i] = (float)lst[i][0];
        fb[i] = (float)lst[i][1];
    }
    float fl[16];
    #pragma unroll
    for (int i = 0; i < 16; i++) fl[i] = fmaxf(fa[i], fb[15 - i]);
    bitonic_clean16_desc(fl);

    // intra-wave merge across quads (lanes with same col16): 2 shfl levels (proven)
    #pragma unroll
    for (int off = 16; off <= 32; off <<= 1) {
        float mg[16];
        #pragma unroll
        for (int i = 0; i < 16; i++)
            mg[i] = fmaxf(fl[i], __shfl_xor(fl[15 - i], off, 64));
        bitonic_clean16_desc(mg);
        #pragma unroll
        for (int i = 0; i < 16; i++) fl[i] = mg[i];
    }

    if (quad == 0) {
        float* outp = topbuf + (((size_t)j * N + row) * ncs + cs) * KTOP;
        #pragma unroll
        for (int k = 0; k < KTOP; k++) outp[k] = fl[k];
    }
}

// ---------------- finalize: up-to-8-way merge + entropy reduce (R7-proven, VERBATIM) ---
__global__ __launch_bounds__(64) void neguni_fin(
    const float* __restrict__ topbuf, float* __restrict__ out, int ncs)
{
    __shared__ float buf[64][8 * 17];   // 8 lists x (16 + tail sentinel) per thread
    __shared__ float buf2[64][4 * 17];  // pre-merged lists (ncs==8 path)
    __shared__ float mm[16][65];        // merged [row_l][k*4+j], padded

    const int t     = threadIdx.x;      // 0..63
    const int j     = t >> 4;           // 0..3
    const int row_l = t & 15;           // 0..15
    const int row   = blockIdx.x * 16 + row_l;

    #pragma unroll
    for (int c = 0; c < 8; c++) {
        if (c < ncs) {
            const float4* src = (const float4*)(topbuf + (((size_t)j * N + row) * ncs + c) * KTOP);
            #pragma unroll
            for (int q = 0; q < 4; q++) {
                float4 v = src[q];
                buf[t][c * 17 + q * 4 + 0] = v.x;
                buf[t][c * 17 + q * 4 + 1] = v.y;
                buf[t][c * 17 + q * 4 + 2] = v.z;
                buf[t][c * 17 + q * 4 + 3] = v.w;
            }
        } else {
            #pragma unroll
            for (int q = 0; q < 16; q++) buf[t][c * 17 + q] = -3.0e38f;
        }
        buf[t][c * 17 + 16] = -3.0e38f;  // tail sentinel
    }

    if (ncs == 8) {
        #pragma unroll
        for (int c = 0; c < 4; c++) {
            int ia = (2 * c) * 17, ib = (2 * c + 1) * 17;
            #pragma unroll
            for (int k = 0; k < KTOP; k++) {
                float va = buf[t][ia], vb = buf[t][ib];
                bool ta = va >= vb;
                buf2[t][c * 17 + k] = ta ? va : vb;
                if (ta) ia++; else ib++;
            }
            buf2[t][c * 17 + 16] = -3.0e38f;
        }
    }

    {
        const float* bb = (ncs == 8) ? buf2[t] : buf[t];
        int i0 = 0, i1 = 17, i2 = 34, i3 = 51;
        #pragma unroll
        for (int k = 0; k < KTOP; k++) {
            float v0 = bb[i0], v1 = bb[i1];
            float v2 = bb[i2], v3 = bb[i3];
            float m01 = fmaxf(v0, v1), m23 = fmaxf(v2, v3);
            float mx  = fmaxf(m01, m23);
            if      (mx == v0) i0++;
            else if (mx == v1) i1++;
            else if (mx == v2) i2++;
            else               i3++;
            mm[row_l][k * 4 + j] = mx;
        }
    }
    __syncthreads();

    float val = 0.f;
    #pragma unroll
    for (int i = 0; i < 4; i++) {
        const int idx2 = t + i * 64;          // 0..255
        const int rl   = idx2 & 15;
        const int k    = idx2 >> 4;           // 0..15
        float l0 = mm[rl][k * 4 + 0] * 100.0f;
        float l1 = mm[rl][k * 4 + 1] * 100.0f;
        float l2 = mm[rl][k * 4 + 2] * 100.0f;
        float l3 = mm[rl][k * 4 + 3] * 100.0f;
        float m  = fmaxf(fmaxf(l0, l1), fmaxf(l2, l3));
        float d0 = l0 - m, d1 = l1 - m, d2 = l2 - m, d3 = l3 - m;
        float e0 = __expf(d0), e1 = __expf(d1), e2 = __expf(d2), e3 = __expf(d3);
        float s  = e0 + e1 + e2 + e3;
        float ent = (e0 * d0 + e1 * d1 + e2 * d2 + e3 * d3) / s - __logf(s);
        float dk  = __expf(-0.05129329439f * (float)k);   // 0.95^k
        val += ent * dk;
    }
    val *= (1.0f / (11.1974666f * (float)N));   // Ssum = (1-0.95^16)/0.05

    #pragma unroll
    for (int off = 32; off > 0; off >>= 1) val += __shfl_xor(val, off, 64);
    if (t == 0) {
        atomicAdd(out, val);
        if (blockIdx.x == 0) atomicAdd(out, 1.38629436112f);   // log(4)
    }
}

extern "C" void kernel_launch(void* const* d_in, const int* in_sizes, int n_in,
                              void* d_out, int out_size, void* d_ws, size_t ws_size,
                              hipStream_t stream) {
    const float* feat   = (const float*)d_in[0];
    const int*   target = (const int*)d_in[1];
    const float* negs   = (const float*)d_in[2];
    const int*   idxp   = (const int*)d_in[3];
    float* out = (float*)d_out;

    unsigned short* fh = (unsigned short*)d_ws;
    unsigned short* gh = fh + (size_t)N * D;                  // +1 MB
    float* topbuf      = (float*)(gh + (size_t)NJ * N * D);   // +5 MB

    // topbuf = NJ*N*ncs*16*4 B: ncs=8 -> 8MB (ws 13MB), ncs=4 -> 4MB (ws 9MB).
    // Deterministic in ws_size only: identical under graph capture.
    const int ncs = (ws_size >= (size_t)13 * 1024 * 1024) ? 8
                  : (ws_size >= (size_t)9  * 1024 * 1024) ? 4 : 2;
    const int nch = 64 / ncs;   // 64-cand chunks per block

    neguni_prep<<<dim3(512), dim3(256), 0, stream>>>(feat, negs, fh, gh, out);
    neguni_main<<<dim3(NJ * 64 * ncs), dim3(256), 0, stream>>>(fh, gh, target, idxp, topbuf, ncs, nch);
    neguni_fin<<<dim3(N / 16), dim3(64), 0, stream>>>(topbuf, out, ncs);
}